// Round 19
// baseline (169.814 us; speedup 1.0000x reference)
//
#include <hip/hip_runtime.h>
#include <hip/hip_bf16.h>

typedef __attribute__((ext_vector_type(8))) short short8v;
typedef __attribute__((ext_vector_type(4))) float f32x4;
typedef __attribute__((ext_vector_type(16))) float f32x16;

constexpr int B_  = 8;
constexpr int NH  = 12;
constexpr int DIM = 768;
constexpr int HD  = 64;
constexpr int N_  = 1025;
constexpr int NSP = 1024;
constexpr int K3  = 2304;
constexpr int VT  = 34;      // kv tiles (33 used; tile 32 padded, 33 unused)

// K_sw / V_sw: fragment-major [bh][VT][4][64][8] ushort (4096 B per tile).
constexpr size_t KV_BYTES = (size_t)B_*NH*VT*4096;

// ---- workspace byte offsets ----
constexpr size_t OFF_MASK  = 0;
constexpr size_t OFF_PC    = 49152;
constexpr size_t OFF_QKVWT = 65536;
constexpr size_t OFF_PROJWT= OFF_QKVWT + (size_t)K3*768*2;
constexpr size_t OFF_Q     = OFF_PROJWT + (size_t)768*768*2;
constexpr size_t OFF_K     = OFF_Q + (size_t)B_*NH*N_*HD*2;
constexpr size_t OFF_V     = OFF_K + KV_BYTES;
constexpr size_t OFF_AO    = OFF_V + KV_BYTES;
constexpr size_t OFF_PS    = OFF_AO + (size_t)8192*768*2;
constexpr size_t OFF_PM    = OFF_PS + 64*768*4;
constexpr size_t OFF_XB    = OFF_PM + 64*768*4;       // x bf16 [8320][768]

__device__ inline float b2f(unsigned short u) {
  union { unsigned int ui; float f; } x; x.ui = ((unsigned int)u) << 16; return x.f;
}
__device__ inline unsigned short f2b(float f) {
  union { float f; unsigned int u; } x; x.f = f;
  unsigned int r = x.u + 0x7FFFu + ((x.u >> 16) & 1u);
  return (unsigned short)(r >> 16);
}
__device__ inline unsigned int cvtpk(float lo, float hi) {
  unsigned int r;
  asm("v_cvt_pk_bf16_f32 %0, %1, %2" : "=v"(r) : "v"(lo), "v"(hi));
  return r;
}
__device__ inline short8v pack8(float4 lo, float4 hi) {
  union { unsigned int u[4]; short8v s; } r;
  r.u[0] = cvtpk(lo.x, lo.y); r.u[1] = cvtpk(lo.z, lo.w);
  r.u[2] = cvtpk(hi.x, hi.y); r.u[3] = cvtpk(hi.z, hi.w);
  return r.s;
}
__device__ inline float fexp2(float x) {
  float r;
  asm("v_exp_f32 %0, %1" : "=v"(r) : "v"(x));
  return r;
}
__device__ inline void plswap(unsigned int& a, unsigned int& b) {
  asm("v_permlane32_swap_b32 %0, %1" : "+v"(a), "+v"(b));
}
__device__ inline void gload16(const void* g, void* l) {
  __builtin_amdgcn_global_load_lds(
      (const __attribute__((address_space(1))) void*)g,
      (__attribute__((address_space(3))) void*)l, 16, 0, 0);
}
template<int NWG>
__device__ inline int xcd_swz(int bid) {
  constexpr int q = NWG / 8, r = NWG % 8;
  const int x = bid & 7, i = bid >> 3;
  return (x < r ? x * (q + 1) : r * (q + 1) + (x - r) * q) + i;
}

// ---------------- merged preprocessing ----------------
__global__ __launch_bounds__(256) void preproc(
    const unsigned char* __restrict__ mraw, float* __restrict__ mask_f,
    float* __restrict__ pcnt, unsigned short* __restrict__ kW,
    unsigned short* __restrict__ vW,
    const float* __restrict__ qkv_w, const float* __restrict__ proj_w,
    unsigned short* __restrict__ qkvwT, unsigned short* __restrict__ projwT,
    const float* __restrict__ x, unsigned short* __restrict__ xb)
{
  const int g = blockIdx.x, t = threadIdx.x;
  if (g < 96) {
    unsigned short* kz = kW + ((size_t)g * VT + 32) * 2048;
    for (int i = t; i < 2048; i += 256) kz[i] = 0;
    unsigned short* vz = vW + ((size_t)g * VT + 32) * 2048;
    for (int i = t; i < 2048; i += 256) vz[i] = 0;
    // zero xb tail rows 8200..8319 (staged by gemm0's last m-tile, outputs
    // discarded, but otherwise uninitialized workspace).
    unsigned short* xz = xb + (size_t)8200 * 768;
    for (int i = g * 256 + t; i < 120 * 768; i += 96 * 256) xz[i] = 0;
    return;
  }
  if (g == 96) {
    __shared__ int flags[2];
    __shared__ float cnt8[8];
    if (t < 2) flags[t] = 0;
    if (t < 8) cnt8[t] = 0.f;
    __syncthreads();
    const int n = B_ * N_;
    int f1 = 0, f0 = 0;
    for (int i = t; i < n; i += 256) {
      unsigned char vv = mraw[i];
      if (vv) { int m = i & 3; if (m == 1) f1 = 1; if (m == 0) f0 = 1; }
    }
    if (f1) atomicOr(&flags[0], 1);
    if (f0) atomicOr(&flags[1], 1);
    __syncthreads();
    const bool isBool = flags[0] != 0;
    const bool isInt  = !isBool && (flags[1] != 0);
    for (int i = t; i < n; i += 256) {
      float v;
      if (isBool)     v = mraw[i] ? 1.f : 0.f;
      else if (isInt) v = ((const int*)mraw)[i] ? 1.f : 0.f;
      else            v = ((const float*)mraw)[i];
      mask_f[i] = v;
      const int b = i / 1025, nn = i - b * 1025;
      if (nn > 0) atomicAdd(&cnt8[b], v);
    }
    __syncthreads();
    if (t < 8) pcnt[t] = cnt8[t];
    return;
  }
  if (g < 2401) {
    __shared__ float tile[32][33];
    const float* in; unsigned short* out; int N, bx, by;
    if (g < 1825) { const int idx = g - 97;  in = qkv_w;  out = qkvwT;  N = K3;  bx = idx % 72; by = idx / 72; }
    else          { const int idx = g - 1825; in = proj_w; out = projwT; N = 768; bx = idx % 24; by = idx / 24; }
    const int tx = t & 31, ty0 = t >> 5;
    const int n0 = bx * 32, k0 = by * 32;
#pragma unroll
    for (int i = 0; i < 4; ++i) {
      const int r = ty0 + i * 8;
      tile[r][tx] = in[(size_t)(k0 + r) * N + n0 + tx];
    }
    __syncthreads();
#pragma unroll
    for (int i = 0; i < 4; ++i) {
      const int r = ty0 + i * 8;
      out[(size_t)(n0 + r) * 768 + k0 + tx] = f2b(tile[tx][r]);
    }
    return;
  }
  const int idx = g - 2401;
  const int n4 = 8200 * 768 / 4;
  for (int i = idx * 256 + t; i < n4; i += 2048 * 256) {
    float4 v = *(const float4*)&x[i * 4];
    ushort4 u;
    u.x = f2b(v.x); u.y = f2b(v.y); u.z = f2b(v.z); u.w = f2b(v.w);
    *(ushort4*)&xb[i * 4] = u;
  }
}

// ---------------- bf16 MFMA GEMM: BK=64, counted-vmcnt double-buffer, ----
// XOR-swizzled LDS (pre-swizzled global source + swizzled ds_read; linear
// gload_lds dest per rule 21). 12 K-steps (was 24) halve barrier/vmcnt
// overhead; slot = col8 ^ (row&7) makes ds_read_b128 2-way (free).
template<int MODE, int GX, int NWG>
__global__ __launch_bounds__(256) void gemm_bf16(
    const unsigned short* __restrict__ A, const unsigned short* __restrict__ BT,
    const float* __restrict__ bias,
    unsigned short* __restrict__ qo, unsigned short* __restrict__ ko,
    unsigned short* __restrict__ vo,
    const float* __restrict__ mask_f, float* __restrict__ psum,
    float* __restrict__ pmax, int M)
{
  __shared__ unsigned short As[2][128 * 64];   // 32 KB
  __shared__ unsigned short Bs[2][128 * 64];   // 32 KB  (total 64 KB)
  const int t = threadIdx.x;
  const int l = t & 63, w = t >> 6;
  const int lg16 = l >> 4, lm16 = l & 15;
  const int wr = w >> 1, wc = w & 1;
  const int wg = xcd_swz<NWG>(blockIdx.x);
  const int by = wg / GX, bx = wg - by * GX;
  const int m0 = by * 128, n0 = bx * 128;

  f32x4 acc[4][4];
#pragma unroll
  for (int i = 0; i < 4; ++i)
#pragma unroll
    for (int j = 0; j < 4; ++j) acc[i][j] = (f32x4){0.f, 0.f, 0.f, 0.f};

  // staging: thread t covers rows (t>>3)+32i, slot t&7; source col8 is
  // pre-swizzled: (t&7) ^ (row&7) so LDS[row][slot] = global col8 slot^(row&7)
  const int srow = t >> 3;
  const int scol = ((t & 7) ^ (srow & 7)) * 8;
  const unsigned short* Asrc0 = A + (size_t)(m0 + srow) * 768 + scol;
  const unsigned short* Bsrc0 = BT + (size_t)(n0 + srow) * 768 + scol;
  char* const Adst = (char*)&As[0][0] + w * 1024;
  char* const Bdst = (char*)&Bs[0][0] + w * 1024;
  constexpr int RS = 32 * 768;      // 32-row source stride (ushorts)
  constexpr int BUF = 128 * 64 * 2; // buffer stride (bytes)

#define STAGE(bi, k0)                                                     \
  do {                                                                    \
    gload16(Asrc0 + (k0),          Adst + (bi) * BUF);                    \
    gload16(Asrc0 + (k0) + RS,     Adst + (bi) * BUF + 4096);             \
    gload16(Asrc0 + (k0) + 2 * RS, Adst + (bi) * BUF + 8192);             \
    gload16(Asrc0 + (k0) + 3 * RS, Adst + (bi) * BUF + 12288);            \
    gload16(Bsrc0 + (k0),          Bdst + (bi) * BUF);                    \
    gload16(Bsrc0 + (k0) + RS,     Bdst + (bi) * BUF + 4096);             \
    gload16(Bsrc0 + (k0) + 2 * RS, Bdst + (bi) * BUF + 8192);             \
    gload16(Bsrc0 + (k0) + 3 * RS, Bdst + (bi) * BUF + 12288);            \
  } while (0)

  STAGE(0, 0);

#pragma unroll
  for (int kk = 0; kk < 12; ++kk) {
    const int cur = kk & 1;
    if (kk < 11) {
      STAGE(cur ^ 1, (kk + 1) * 64);
      asm volatile("s_waitcnt vmcnt(8)" ::: "memory");
    } else {
      asm volatile("s_waitcnt vmcnt(0)" ::: "memory");
    }
    asm volatile("s_barrier" ::: "memory");
#pragma unroll
    for (int ksub = 0; ksub < 2; ++ksub) {
      short8v af[4], bf4[4];
#pragma unroll
      for (int mi = 0; mi < 4; ++mi) {
        const int R = wr * 64 + mi * 16 + lm16;
        af[mi] = *(const short8v*)
            &As[cur][R * 64 + (((ksub * 4 + lg16) ^ (R & 7)) * 8)];
      }
#pragma unroll
      for (int ni = 0; ni < 4; ++ni) {
        const int R = wc * 64 + ni * 16 + lm16;
        bf4[ni] = *(const short8v*)
            &Bs[cur][R * 64 + (((ksub * 4 + lg16) ^ (R & 7)) * 8)];
      }
#pragma unroll
      for (int mi = 0; mi < 4; ++mi)
#pragma unroll
        for (int ni = 0; ni < 4; ++ni)
          acc[mi][ni] = __builtin_amdgcn_mfma_f32_16x16x32_bf16(
              af[mi], bf4[ni], acc[mi][ni], 0, 0, 0);
    }
    asm volatile("s_barrier" ::: "memory");
  }
#undef STAGE

  if (MODE == 1) {
    __syncthreads();
    float* sred = (float*)&As[0][0];
    float* xred = sred + 256;
    const int b0 = m0 >> 10, nr = m0 & 1023;
#pragma unroll
    for (int ni = 0; ni < 4; ++ni) {
      const int cidx = wc * 64 + ni * 16 + lm16;
      const float bv = bias[n0 + cidx];
      float s = 0.f, xm = -3.402823466e+38f;
#pragma unroll
      for (int mi = 0; mi < 4; ++mi)
#pragma unroll
        for (int r = 0; r < 4; ++r) {
          const float v = acc[mi][ni][r] + bv;
          const float m =
              mask_f[b0 * N_ + 1 + nr + wr * 64 + mi * 16 + lg16 * 4 + r];
          s = fmaf(v, m, s);
          xm = fmaxf(xm, v);
        }
      s += __shfl_xor(s, 16);
      s += __shfl_xor(s, 32);
      xm = fmaxf(xm, __shfl_xor(xm, 16));
      xm = fmaxf(xm, __shfl_xor(xm, 32));
      if (lg16 == 0) {
        sred[wr * 128 + cidx] = s;
        xred[wr * 128 + cidx] = xm;
      }
    }
    __syncthreads();
    if (t < 128) {
      const float s  = sred[t] + sred[128 + t];
      const float xm = fmaxf(xred[t], xred[128 + t]);
      psum[(size_t)by * 768 + n0 + t] = s;
      pmax[(size_t)by * 768 + n0 + t] = xm;
    }
  } else {
#pragma unroll
    for (int mi = 0; mi < 4; ++mi) {
      const int r0 = m0 + wr * 64 + mi * 16 + lg16 * 4;
      const int b0d = r0 / 1025;
      const int n0d = r0 - b0d * 1025;
#pragma unroll
      for (int ni = 0; ni < 4; ++ni) {
        const int col = n0 + wc * 64 + ni * 16 + lm16;
        const int which = col / 768;
        const int rem = col - which * 768;
        const int head = rem >> 6, d = rem & 63;
        const float bv = bias[col];
#pragma unroll
        for (int r = 0; r < 4; ++r) {
          const int grow = r0 + r;
          if (grow >= M) continue;
          int b = b0d, n = n0d + r;
          if (n >= 1025) { b += 1; n -= 1025; }
          const unsigned short val = f2b(acc[mi][ni][r] + bv);
          const int bh = b * NH + head;
          if (which == 0) {
            qo[((size_t)bh * N_ + n) * HD + d] = val;
          } else if (which == 1) {
            ko[((size_t)bh * VT + (n >> 5)) * 2048 + (d >> 4) * 512 +
               ((((d >> 3) & 1) << 5) + (n & 31)) * 8 + (d & 7)] = val;
          } else {
            const int kvloc = n & 31;
            vo[((size_t)bh * VT + (n >> 5)) * 2048 +
               ((d >> 5) * 2 + (kvloc >> 4)) * 512 +
               ((((kvloc >> 3) & 1) << 5) + (d & 31)) * 8 + (kvloc & 7)] = val;
          }
        }
      }
    }
  }
}

// ---------------- MFMA flash attention v10 (R14 exact; THR 2 nats) -------
__global__ __launch_bounds__(256, 3) void attn_mfma(
    const unsigned short* __restrict__ qp, const unsigned short* __restrict__ kp,
    const unsigned short* __restrict__ vp, const float* __restrict__ mask_f,
    const float* __restrict__ rph, const float* __restrict__ rpw,
    unsigned short* __restrict__ ao)
{
  const int bid = blockIdx.x;
  const int xcd = bid & 7, wx = bid >> 3;
  const int qblk = wx / 12, hl = wx - qblk * 12;
  const int bh = xcd * 12 + hl;
  const int b = bh / NH, head = bh - b * NH;

  const int t = threadIdx.x, w = t >> 6, lane = t & 63;
  const int qi = lane & 31, h = lane >> 5;
  const int row = w * 32 + qi;
  constexpr float L2E = 1.44269504f;
  constexpr float SCL = 0.125f * L2E;
  constexpr float MCOL = -1.44269504e9f;
  constexpr float THR_L = 2.885f;

  __shared__ __align__(16) float bh_lds[128][34];
  __shared__ __align__(16) float ct_lds[1088];
  __shared__ __align__(16) unsigned short T16[128][64];
  float* ctm = (float*)&T16[0][0];

  const unsigned short* qbp = qp + (size_t)bh * N_ * HD;
  const unsigned short* kbp = kp + (size_t)bh * VT * 2048;
  const unsigned short* vbp = vp + (size_t)bh * VT * 2048;
  const int qw0 = qblk * 128 + w * 32;
  const int q = qw0 + qi;

  for (int i = t; i < 1088; i += 256)
    ct_lds[i] = (i < N_) ? (MCOL * (1.f - mask_f[b * N_ + i])) : -2e30f;

  short8v qf[4];
#pragma unroll
  for (int c = 0; c < 4; ++c)
    qf[c] = *(const short8v*)&qbp[(size_t)(1 + q) * HD + c * 16 + h * 8];

  {
    const int hq = q >> 5;
    f32x16 sbh = {}, sb1 = {}, sb2 = {};
    const float* rh0 = rph + (size_t)(hq + 31 - qi) * HD + h * 8;
    const float* rw1 = rpw + (size_t)qi * HD + h * 8;
    const float* rw2 = rpw + (size_t)(qi < 31 ? 32 + qi : 62) * HD + h * 8;
#pragma unroll
    for (int c = 0; c < 4; ++c) {
      short8v a1 = pack8(*(const float4*)(rh0 + c * 16), *(const float4*)(rh0 + c * 16 + 4));
      sbh = __builtin_amdgcn_mfma_f32_32x32x16_bf16(a1, qf[c], sbh, 0, 0, 0);
      short8v a2 = pack8(*(const float4*)(rw1 + c * 16), *(const float4*)(rw1 + c * 16 + 4));
      sb1 = __builtin_amdgcn_mfma_f32_32x32x16_bf16(a2, qf[c], sb1, 0, 0, 0);
      short8v a3 = pack8(*(const float4*)(rw2 + c * 16), *(const float4*)(rw2 + c * 16 + 4));
      sb2 = __builtin_amdgcn_mfma_f32_32x32x16_bf16(a3, qf[c], sb2, 0, 0, 0);
    }
#pragma unroll
    for (int r = 0; r < 16; ++r) {
      const int kh = (r & 3) + 8 * (r >> 2) + 4 * h;
      bh_lds[row][kh]   = sbh[r] * L2E;
      T16[row][kh]      = f2b(sb1[r] * L2E);
      T16[row][kh + 32] = f2b(sb2[r] * L2E);
    }
    if (h == 0) { bh_lds[row][32] = 0.f; bh_lds[row][33] = 0.f; }
  }
  __syncthreads();

  float bwv[16];
#pragma unroll
  for (int r = 0; r < 16; ++r) {
    const int kvS = (r & 3) + 8 * (r >> 2) + 4 * h;
    const int kw = (kvS + 31) & 31;
    bwv[r] = b2f(T16[row][qi - kw + 31]);
  }
  __syncthreads();
  for (int i = t; i < 1088; i += 256)
    ctm[i] = (i <= 1024) ? MCOL : -2e30f;
  __syncthreads();

  const float mi_s = mask_f[b * N_ + 1 + q];
  const bool mzero = (mi_s == 0.f);
  const float* ctp = mzero ? ctm : ct_lds;
  const float h0sel = (h == 0) ? 1.f : 0.f;
  float m_lm = -1e30f, l_lane = 0.f;
  float bh_prev = -bwv[0];
  f32x16 oaccA = {}, oaccB = {};

  const char* kptr = (const char*)kbp + lane * 16;
  const char* vptr = (const char*)vbp + lane * 16;

  short8v kf[4];
#pragma unroll
  for (int c = 0; c < 4; ++c) kf[c] = *(const short8v*)(kptr + c * 1024);
  kptr += 4096;
  f32x16 sP = {}, sQ = {};
  sP = __builtin_amdgcn_mfma_f32_32x32x16_bf16(kf[0], qf[0], sP, 0, 0, 0);
  sP = __builtin_amdgcn_mfma_f32_32x32x16_bf16(kf[1], qf[1], sP, 0, 0, 0);
  sP = __builtin_amdgcn_mfma_f32_32x32x16_bf16(kf[2], qf[2], sP, 0, 0, 0);
  sP = __builtin_amdgcn_mfma_f32_32x32x16_bf16(kf[3], qf[3], sP, 0, 0, 0);

#define AITER(KT, SC, SN, DOPREF)                                            \
  do {                                                                       \
    short8v vf00 = *(const short8v*)(vptr);                                  \
    short8v vf01 = *(const short8v*)(vptr + 1024);                           \
    short8v vf10 = *(const short8v*)(vptr + 2048);                           \
    short8v vf11 = *(const short8v*)(vptr + 3072);                           \
    vptr += 4096;                                                            \
    if (DOPREF) {                                                            \
      kf[0] = *(const short8v*)(kptr);                                       \
      kf[1] = *(const short8v*)(kptr + 1024);                                \
      kf[2] = *(const short8v*)(kptr + 2048);                                \
      kf[3] = *(const short8v*)(kptr + 3072);                                \
      kptr += 4096;                                                          \
    }                                                                        \
    const float bh_k = bh_lds[row][KT];                                      \
    const float bh_use = mzero ? 0.f : bh_k;                                 \
    f32x4 ct4[4];                                                            \
    ct4[0] = *(const f32x4*)&ctp[(KT) * 32 + h * 4];                         \
    ct4[1] = *(const f32x4*)&ctp[(KT) * 32 + 8 + h * 4];                     \
    ct4[2] = *(const f32x4*)&ctp[(KT) * 32 + 16 + h * 4];                    \
    ct4[3] = *(const f32x4*)&ctp[(KT) * 32 + 24 + h * 4];                    \
    float lgp[16];                                                           \
    _Pragma("unroll")                                                        \
    for (int r = 0; r < 16; ++r)                                             \
      lgp[r] = fmaf(SCL, SC[r], bwv[r] + ct4[r >> 2][r & 3]);                \
    lgp[0] = fmaf(h0sel, bh_prev - bh_use, lgp[0]);                          \
    bh_prev = bh_k;                                                          \
    float a0 = fmaxf(lgp[0], lgp[1]),  a1 = fmaxf(lgp[2], lgp[3]);           \
    float a2 = fmaxf(lgp[4], lgp[5]),  a3 = fmaxf(lgp[6], lgp[7]);           \
    float a4 = fmaxf(lgp[8], lgp[9]),  a5 = fmaxf(lgp[10], lgp[11]);         \
    float a6 = fmaxf(lgp[12], lgp[13]), a7 = fmaxf(lgp[14], lgp[15]);        \
    float tm = fmaxf(fmaxf(fmaxf(a0, a1), fmaxf(a2, a3)),                    \
                     fmaxf(fmaxf(a4, a5), fmaxf(a6, a7)));                   \
    tm = fmaxf(tm, __shfl_xor(tm, 32));                                      \
    const float tmT = tm + bh_use;                                           \
    if (__any(tmT > m_lm + THR_L)) {                                         \
      const float nm = fmaxf(m_lm, tmT);                                     \
      const float rf = fexp2(m_lm - nm);                                     \
      m_lm = nm; l_lane *= rf;                                               \
      _Pragma("unroll")                                                      \
      for (int r = 0; r < 16; ++r) { oaccA[r] *= rf; oaccB[r] *= rf; }       \
    }                                                                        \
    const float mm = bh_use - m_lm;                                          \
    float p[16];                                                             \
    _Pragma("unroll")                                                        \
    for (int r = 0; r < 16; ++r) p[r] = fexp2(lgp[r] + mm);                  \
    l_lane += (((p[0]+p[1])+(p[2]+p[3]))+((p[4]+p[5])+(p[6]+p[7])))          \
            + (((p[8]+p[9])+(p[10]+p[11]))+((p[12]+p[13])+(p[14]+p[15])));   \
    unsigned int x0 = cvtpk(p[0], p[1]),  x1 = cvtpk(p[2], p[3]);            \
    unsigned int z0 = cvtpk(p[4], p[5]),  z1 = cvtpk(p[6], p[7]);            \
    plswap(x0, z0); plswap(x1, z1);                                          \
    unsigned int y0 = cvtpk(p[8], p[9]),  y1 = cvtpk(p[10], p[11]);          \
    unsigned int w0_ = cvtpk(p[12], p[13]), w1_ = cvtpk(p[14], p[15]);       \
    plswap(y0, w0_); plswap(y1, w1_);                                        \
    union { unsigned int u[4]; short8v v; } uf1, uf2;                        \
    uf1.u[0] = x0; uf1.u[1] = x1; uf1.u[2] = z0; uf1.u[3] = z1;              \
    uf2.u[0] = y0; uf2.u[1] = y1; uf2.u[2] = w0_; uf2.u[3] = w1_;            \
    if (DOPREF) {                                                            \
      f32x16 sn = {};                                                        \
      sn = __builtin_amdgcn_mfma_f32_32x32x16_bf16(kf[0], qf[0], sn, 0, 0, 0); \
      sn = __builtin_amdgcn_mfma_f32_32x32x16_bf16(kf[1], qf[1], sn, 0, 0, 0); \
      sn = __builtin_amdgcn_mfma_f32_32x32x16_bf16(kf[2], qf[2], sn, 0, 0, 0); \
      sn = __builtin_amdgcn_mfma_f32_32x32x16_bf16(kf[3], qf[3], sn, 0, 0, 0); \
      SN = sn;                                                               \
    }                                                                        \
    oaccA = __builtin_amdgcn_mfma_f32_32x32x16_bf16(vf00, uf1.v, oaccA, 0, 0, 0); \
    oaccA = __builtin_amdgcn_mfma_f32_32x32x16_bf16(vf01, uf2.v, oaccA, 0, 0, 0); \
    oaccB = __builtin_amdgcn_mfma_f32_32x32x16_bf16(vf10, uf1.v, oaccB, 0, 0, 0); \
    oaccB = __builtin_amdgcn_mfma_f32_32x32x16_bf16(vf11, uf2.v, oaccB, 0, 0, 0); \
  } while (0)

  for (int kt2 = 0; kt2 < 16; ++kt2) {
    AITER(2 * kt2,     sP, sQ, true);
    AITER(2 * kt2 + 1, sQ, sP, true);
  }
  AITER(32, sP, sQ, false);
#undef AITER

  // RACE FIX barrier: ctm (aliased in T16) reads must finish before the
  // epilogue overwrites T16.
  __syncthreads();

  const float l_tot = l_lane + __shfl_xor(l_lane, 32);
  const float inv = 1.f / l_tot;
  char* tbase = (char*)&T16[0][0] + row * 128;
  const int rsw = (row & 7) << 4;
#pragma unroll
  for (int r = 0; r < 16; r += 2) {
    const int d = (r & 3) + 8 * (r >> 2) + 4 * h;
    const unsigned int uA = cvtpk(oaccA[r] * inv, oaccA[r + 1] * inv);
    const unsigned int uB = cvtpk(oaccB[r] * inv, oaccB[r + 1] * inv);
    const int bo1 = 2 * d, bo2 = 2 * d + 64;
    *(unsigned int*)(tbase + (((bo1 & ~15) ^ rsw) | (bo1 & 15))) = uA;
    *(unsigned int*)(tbase + (((bo2 & ~15) ^ rsw) | (bo2 & 15))) = uB;
  }
  const int q2 = lane >> 1, hb = lane & 1;
  const int srow = w * 32 + q2;
  const char* sbase = (const char*)&T16[0][0] + srow * 128;
  const int ssw = srow & 7;
  unsigned short* dst =
      ao + (size_t)(b * NSP + qw0 + q2) * DIM + head * HD + hb * 32;
#pragma unroll
  for (int i = 0; i < 4; ++i) {
    const int ci = hb * 4 + i;
    short8v v = *(const short8v*)(sbase + ((ci ^ ssw) << 4));
    *(short8v*)(dst + i * 8) = v;
  }
}

// ---------------- final pooling reduce ----------------
__global__ __launch_bounds__(256) void pool_stage2(
    const float* __restrict__ psum, const float* __restrict__ pmax,
    const float* __restrict__ pcnt, float* __restrict__ out)
{
  const int b = blockIdx.y;
  const int c = blockIdx.x * 256 + threadIdx.x;
  float s = 0.f, mx = -3.402823466e+38f;
#pragma unroll
  for (int z = 0; z < 8; ++z) {
    s  += psum[(size_t)(b * 8 + z) * 768 + c];
    mx  = fmaxf(mx, pmax[(size_t)(b * 8 + z) * 768 + c]);
  }
  const float cnt = pcnt[b];
  out[b * 1536 + c]       = s / (cnt + 1e-7f);
  out[b * 1536 + 768 + c] = mx;
}

// ---------------- launch ----------------
extern "C" void kernel_launch(void* const* d_in, const int* in_sizes, int n_in,
                              void* d_out, int out_size, void* d_ws, size_t ws_size,
                              hipStream_t stream) {
  const float* x      = (const float*)d_in[0];
  const unsigned char* mraw = (const unsigned char*)d_in[1];
  const float* qkv_w  = (const float*)d_in[2];
  const float* qkv_b  = (const float*)d_in[3];
  const float* proj_w = (const float*)d_in[4];
  const float* proj_b = (const float*)d_in[5];
  const float* rph    = (const float*)d_in[6];
  const float* rpw    = (const float*)d_in[7];

  char* ws = (char*)d_ws;
  float*          mask_f = (float*)(ws + OFF_MASK);
  float*          pcnt   = (float*)(ws + OFF_PC);
  unsigned short* qkvwT  = (unsigned short*)(ws + OFF_QKVWT);
  unsigned short* projwT = (unsigned short*)(ws + OFF_PROJWT);
  unsigned short* qW     = (unsigned short*)(ws + OFF_Q);
  unsigned short* kW     = (unsigned short*)(ws + OFF_K);
  unsigned short* vW     = (unsigned short*)(ws + OFF_V);
  unsigned short* aoW    = (unsigned short*)(ws + OFF_AO);
  float*          psum   = (float*)(ws + OFF_PS);
  float*          pmax   = (float*)(ws + OFF_PM);
  unsigned short* xb     = (unsigned short*)(ws + OFF_XB);

  preproc<<<4449, 256, 0, stream>>>(mraw, mask_f, pcnt, kW, vW,
                                    qkv_w, proj_w, qkvwT, projwT, x, xb);

  gemm_bf16<0, 18, 1170><<<1170, 256, 0, stream>>>(
      xb, qkvwT, qkv_b, qW, kW, vW, nullptr, nullptr, nullptr, 8200);

  attn_mfma<<<768, 256, 0, stream>>>(qW, kW, vW, mask_f, rph, rpw, aoW);

  gemm_bf16<1, 6, 384><<<384, 256, 0, stream>>>(
      aoW, projwT, proj_b, nullptr, nullptr, nullptr,
      mask_f, psum, pmax, 8192);

  pool_stage2<<<dim3(3, B_), 256, 0, stream>>>(psum, pmax, pcnt, (float*)d_out);
}

// Round 20
// 160.763 us; speedup vs baseline: 1.0563x; 1.0563x over previous
//
#include <hip/hip_runtime.h>
#include <hip/hip_bf16.h>

typedef __attribute__((ext_vector_type(8))) short short8v;
typedef __attribute__((ext_vector_type(4))) float f32x4;
typedef __attribute__((ext_vector_type(16))) float f32x16;

constexpr int B_  = 8;
constexpr int NH  = 12;
constexpr int DIM = 768;
constexpr int HD  = 64;
constexpr int N_  = 1025;
constexpr int NSP = 1024;
constexpr int K3  = 2304;
constexpr int VT  = 34;      // kv tiles (33 used; tile 32 padded, 33 unused)

// K_sw / V_sw: fragment-major [bh][VT][4][64][8] ushort (4096 B per tile).
constexpr size_t KV_BYTES = (size_t)B_*NH*VT*4096;

// ---- workspace byte offsets ----
constexpr size_t OFF_MASK  = 0;
constexpr size_t OFF_PC    = 49152;
constexpr size_t OFF_QKVWT = 65536;
constexpr size_t OFF_PROJWT= OFF_QKVWT + (size_t)K3*768*2;
constexpr size_t OFF_Q     = OFF_PROJWT + (size_t)768*768*2;
constexpr size_t OFF_K     = OFF_Q + (size_t)B_*NH*N_*HD*2;
constexpr size_t OFF_V     = OFF_K + KV_BYTES;
constexpr size_t OFF_AO    = OFF_V + KV_BYTES;
constexpr size_t OFF_PS    = OFF_AO + (size_t)8192*768*2;
constexpr size_t OFF_PM    = OFF_PS + 64*768*4;
constexpr size_t OFF_XB    = OFF_PM + 64*768*4;       // x bf16 [8320][768]

__device__ inline float b2f(unsigned short u) {
  union { unsigned int ui; float f; } x; x.ui = ((unsigned int)u) << 16; return x.f;
}
__device__ inline unsigned short f2b(float f) {
  union { float f; unsigned int u; } x; x.f = f;
  unsigned int r = x.u + 0x7FFFu + ((x.u >> 16) & 1u);
  return (unsigned short)(r >> 16);
}
__device__ inline unsigned int cvtpk(float lo, float hi) {
  unsigned int r;
  asm("v_cvt_pk_bf16_f32 %0, %1, %2" : "=v"(r) : "v"(lo), "v"(hi));
  return r;
}
__device__ inline short8v pack8(float4 lo, float4 hi) {
  union { unsigned int u[4]; short8v s; } r;
  r.u[0] = cvtpk(lo.x, lo.y); r.u[1] = cvtpk(lo.z, lo.w);
  r.u[2] = cvtpk(hi.x, hi.y); r.u[3] = cvtpk(hi.z, hi.w);
  return r.s;
}
__device__ inline float fexp2(float x) {
  float r;
  asm("v_exp_f32 %0, %1" : "=v"(r) : "v"(x));
  return r;
}
__device__ inline void plswap(unsigned int& a, unsigned int& b) {
  asm("v_permlane32_swap_b32 %0, %1" : "+v"(a), "+v"(b));
}
__device__ inline void gload16(const void* g, void* l) {
  __builtin_amdgcn_global_load_lds(
      (const __attribute__((address_space(1))) void*)g,
      (__attribute__((address_space(3))) void*)l, 16, 0, 0);
}
template<int NWG>
__device__ inline int xcd_swz(int bid) {
  constexpr int q = NWG / 8, r = NWG % 8;
  const int x = bid & 7, i = bid >> 3;
  return (x < r ? x * (q + 1) : r * (q + 1) + (x - r) * q) + i;
}

// ---------------- merged preprocessing ----------------
__global__ __launch_bounds__(256) void preproc(
    const unsigned char* __restrict__ mraw, float* __restrict__ mask_f,
    float* __restrict__ pcnt, unsigned short* __restrict__ kW,
    unsigned short* __restrict__ vW,
    const float* __restrict__ qkv_w, const float* __restrict__ proj_w,
    unsigned short* __restrict__ qkvwT, unsigned short* __restrict__ projwT,
    const float* __restrict__ x, unsigned short* __restrict__ xb)
{
  const int g = blockIdx.x, t = threadIdx.x;
  if (g < 96) {
    unsigned short* kz = kW + ((size_t)g * VT + 32) * 2048;
    for (int i = t; i < 2048; i += 256) kz[i] = 0;
    unsigned short* vz = vW + ((size_t)g * VT + 32) * 2048;
    for (int i = t; i < 2048; i += 256) vz[i] = 0;
    // zero xb tail rows 8200..8319 (staged by gemm0's last m-tile, outputs
    // discarded, but otherwise uninitialized workspace).
    unsigned short* xz = xb + (size_t)8200 * 768;
    for (int i = g * 256 + t; i < 120 * 768; i += 96 * 256) xz[i] = 0;
    return;
  }
  if (g == 96) {
    __shared__ int flags[2];
    __shared__ float cnt8[8];
    if (t < 2) flags[t] = 0;
    if (t < 8) cnt8[t] = 0.f;
    __syncthreads();
    const int n = B_ * N_;
    int f1 = 0, f0 = 0;
    for (int i = t; i < n; i += 256) {
      unsigned char vv = mraw[i];
      if (vv) { int m = i & 3; if (m == 1) f1 = 1; if (m == 0) f0 = 1; }
    }
    if (f1) atomicOr(&flags[0], 1);
    if (f0) atomicOr(&flags[1], 1);
    __syncthreads();
    const bool isBool = flags[0] != 0;
    const bool isInt  = !isBool && (flags[1] != 0);
    for (int i = t; i < n; i += 256) {
      float v;
      if (isBool)     v = mraw[i] ? 1.f : 0.f;
      else if (isInt) v = ((const int*)mraw)[i] ? 1.f : 0.f;
      else            v = ((const float*)mraw)[i];
      mask_f[i] = v;
      const int b = i / 1025, nn = i - b * 1025;
      if (nn > 0) atomicAdd(&cnt8[b], v);
    }
    __syncthreads();
    if (t < 8) pcnt[t] = cnt8[t];
    return;
  }
  if (g < 2401) {
    __shared__ float tile[32][33];
    const float* in; unsigned short* out; int N, bx, by;
    if (g < 1825) { const int idx = g - 97;  in = qkv_w;  out = qkvwT;  N = K3;  bx = idx % 72; by = idx / 72; }
    else          { const int idx = g - 1825; in = proj_w; out = projwT; N = 768; bx = idx % 24; by = idx / 24; }
    const int tx = t & 31, ty0 = t >> 5;
    const int n0 = bx * 32, k0 = by * 32;
#pragma unroll
    for (int i = 0; i < 4; ++i) {
      const int r = ty0 + i * 8;
      tile[r][tx] = in[(size_t)(k0 + r) * N + n0 + tx];
    }
    __syncthreads();
#pragma unroll
    for (int i = 0; i < 4; ++i) {
      const int r = ty0 + i * 8;
      out[(size_t)(n0 + r) * 768 + k0 + tx] = f2b(tile[tx][r]);
    }
    return;
  }
  const int idx = g - 2401;
  const int n4 = 8200 * 768 / 4;
  for (int i = idx * 256 + t; i < n4; i += 2048 * 256) {
    float4 v = *(const float4*)&x[i * 4];
    ushort4 u;
    u.x = f2b(v.x); u.y = f2b(v.y); u.z = f2b(v.z); u.w = f2b(v.w);
    *(ushort4*)&xb[i * 4] = u;
  }
}

// ---------------- bf16 MFMA GEMM, counted-vmcnt double-buffer (R14/R18) ---
// Per K-step: STAGE(next) -> vmcnt(4) -> barrier -> ds_read+MFMA -> barrier.
// NOTE (R19 lesson): BK=64 + LDS XOR-swizzle removed all bank conflicts but
// REGRESSED (occupancy 24->16%, FETCH 35->50MB): at a 2-phase schedule the
// critical path is stage+vmcnt+barrier, so LDS-read conflicts are hidden
// (T2 regime gate). This BK=32 2-buffer config measured 162.1us, absmax
// 2.44e-4 — best known.
template<int MODE, int GX, int NWG>
__global__ __launch_bounds__(256) void gemm_bf16(
    const unsigned short* __restrict__ A, const unsigned short* __restrict__ BT,
    const float* __restrict__ bias,
    unsigned short* __restrict__ qo, unsigned short* __restrict__ ko,
    unsigned short* __restrict__ vo,
    const float* __restrict__ mask_f, float* __restrict__ psum,
    float* __restrict__ pmax, int M)
{
  __shared__ unsigned short As[2][128 * 32];
  __shared__ unsigned short Bs[2][128 * 32];
  __shared__ float Ms[128];
  const int t = threadIdx.x;
  const int l = t & 63, w = t >> 6;
  const int lg16 = l >> 4, lm16 = l & 15;
  const int wr = w >> 1, wc = w & 1;
  const int wg = xcd_swz<NWG>(blockIdx.x);
  const int by = wg / GX, bx = wg - by * GX;
  const int m0 = by * 128, n0 = bx * 128;

  if (MODE == 1 && t < 128) {
    const int b0 = m0 >> 10, nr = m0 & 1023;
    Ms[t] = mask_f[b0 * N_ + 1 + nr + t];
  }

  f32x4 acc[4][4];
#pragma unroll
  for (int i = 0; i < 4; ++i)
#pragma unroll
    for (int j = 0; j < 4; ++j) acc[i][j] = (f32x4){0.f, 0.f, 0.f, 0.f};

  const int row0 = t >> 2, qq = (t & 3) * 8;
  const unsigned short* Asrc0 = A + (size_t)(m0 + row0) * 768 + qq;
  const unsigned short* Asrc1 = A + (size_t)(m0 + row0 + 64) * 768 + qq;
  const unsigned short* Bsrc0 = BT + (size_t)(n0 + row0) * 768 + qq;
  const unsigned short* Bsrc1 = BT + (size_t)(n0 + row0 + 64) * 768 + qq;

#define STAGE(bi, k0)                                                    \
  do {                                                                   \
    gload16(Asrc0 + (k0), (char*)&As[bi][0] + w * 1024);                 \
    gload16(Asrc1 + (k0), (char*)&As[bi][0] + 4096 + w * 1024);          \
    gload16(Bsrc0 + (k0), (char*)&Bs[bi][0] + w * 1024);                 \
    gload16(Bsrc1 + (k0), (char*)&Bs[bi][0] + 4096 + w * 1024);          \
  } while (0)

  STAGE(0, 0);

#pragma unroll
  for (int kk = 0; kk < 24; ++kk) {
    const int cur = kk & 1;
    if (kk < 23) {
      STAGE(cur ^ 1, (kk + 1) * 32);
      asm volatile("s_waitcnt vmcnt(4)" ::: "memory");
    } else {
      asm volatile("s_waitcnt vmcnt(0)" ::: "memory");
    }
    asm volatile("s_barrier" ::: "memory");
    short8v af[4], bf4[4];
#pragma unroll
    for (int mi = 0; mi < 4; ++mi)
      af[mi] = *(const short8v*)&As[cur][(wr * 64 + mi * 16 + lm16) * 32 + lg16 * 8];
#pragma unroll
    for (int ni = 0; ni < 4; ++ni)
      bf4[ni] = *(const short8v*)&Bs[cur][(wc * 64 + ni * 16 + lm16) * 32 + lg16 * 8];
#pragma unroll
    for (int mi = 0; mi < 4; ++mi)
#pragma unroll
      for (int ni = 0; ni < 4; ++ni)
        acc[mi][ni] = __builtin_amdgcn_mfma_f32_16x16x32_bf16(
            af[mi], bf4[ni], acc[mi][ni], 0, 0, 0);
    asm volatile("s_barrier" ::: "memory");
  }
#undef STAGE

  if (MODE == 1) {
    __syncthreads();
    float* sred = (float*)&As[0][0];
    float* xred = sred + 256;
#pragma unroll
    for (int ni = 0; ni < 4; ++ni) {
      const int cidx = wc * 64 + ni * 16 + lm16;
      const float bv = bias[n0 + cidx];
      float s = 0.f, xm = -3.402823466e+38f;
#pragma unroll
      for (int mi = 0; mi < 4; ++mi)
#pragma unroll
        for (int r = 0; r < 4; ++r) {
          const float v = acc[mi][ni][r] + bv;
          const float m = Ms[wr * 64 + mi * 16 + lg16 * 4 + r];
          s = fmaf(v, m, s);
          xm = fmaxf(xm, v);
        }
      s += __shfl_xor(s, 16);
      s += __shfl_xor(s, 32);
      xm = fmaxf(xm, __shfl_xor(xm, 16));
      xm = fmaxf(xm, __shfl_xor(xm, 32));
      if (lg16 == 0) {
        sred[wr * 128 + cidx] = s;
        xred[wr * 128 + cidx] = xm;
      }
    }
    __syncthreads();
    if (t < 128) {
      const float s  = sred[t] + sred[128 + t];
      const float xm = fmaxf(xred[t], xred[128 + t]);
      psum[(size_t)by * 768 + n0 + t] = s;
      pmax[(size_t)by * 768 + n0 + t] = xm;
    }
  } else {
#pragma unroll
    for (int mi = 0; mi < 4; ++mi) {
      const int r0 = m0 + wr * 64 + mi * 16 + lg16 * 4;
      const int b0d = r0 / 1025;
      const int n0d = r0 - b0d * 1025;
#pragma unroll
      for (int ni = 0; ni < 4; ++ni) {
        const int col = n0 + wc * 64 + ni * 16 + lm16;
        const int which = col / 768;
        const int rem = col - which * 768;
        const int head = rem >> 6, d = rem & 63;
        const float bv = bias[col];
#pragma unroll
        for (int r = 0; r < 4; ++r) {
          const int grow = r0 + r;
          if (grow >= M) continue;
          int b = b0d, n = n0d + r;
          if (n >= 1025) { b += 1; n -= 1025; }
          const unsigned short val = f2b(acc[mi][ni][r] + bv);
          const int bh = b * NH + head;
          if (which == 0) {
            qo[((size_t)bh * N_ + n) * HD + d] = val;
          } else if (which == 1) {
            ko[((size_t)bh * VT + (n >> 5)) * 2048 + (d >> 4) * 512 +
               ((((d >> 3) & 1) << 5) + (n & 31)) * 8 + (d & 7)] = val;
          } else {
            const int kvloc = n & 31;
            vo[((size_t)bh * VT + (n >> 5)) * 2048 +
               ((d >> 5) * 2 + (kvloc >> 4)) * 512 +
               ((((kvloc >> 3) & 1) << 5) + (d & 31)) * 8 + (kvloc & 7)] = val;
          }
        }
      }
    }
  }
}

// ---------------- MFMA flash attention v10 (R14 exact; THR 2 nats) -------
__global__ __launch_bounds__(256, 3) void attn_mfma(
    const unsigned short* __restrict__ qp, const unsigned short* __restrict__ kp,
    const unsigned short* __restrict__ vp, const float* __restrict__ mask_f,
    const float* __restrict__ rph, const float* __restrict__ rpw,
    unsigned short* __restrict__ ao)
{
  const int bid = blockIdx.x;
  const int xcd = bid & 7, wx = bid >> 3;
  const int qblk = wx / 12, hl = wx - qblk * 12;
  const int bh = xcd * 12 + hl;
  const int b = bh / NH, head = bh - b * NH;

  const int t = threadIdx.x, w = t >> 6, lane = t & 63;
  const int qi = lane & 31, h = lane >> 5;
  const int row = w * 32 + qi;
  constexpr float L2E = 1.44269504f;
  constexpr float SCL = 0.125f * L2E;
  constexpr float MCOL = -1.44269504e9f;
  constexpr float THR_L = 2.885f;

  __shared__ __align__(16) float bh_lds[128][34];
  __shared__ __align__(16) float ct_lds[1088];
  __shared__ __align__(16) unsigned short T16[128][64];
  float* ctm = (float*)&T16[0][0];

  const unsigned short* qbp = qp + (size_t)bh * N_ * HD;
  const unsigned short* kbp = kp + (size_t)bh * VT * 2048;
  const unsigned short* vbp = vp + (size_t)bh * VT * 2048;
  const int qw0 = qblk * 128 + w * 32;
  const int q = qw0 + qi;

  for (int i = t; i < 1088; i += 256)
    ct_lds[i] = (i < N_) ? (MCOL * (1.f - mask_f[b * N_ + i])) : -2e30f;

  short8v qf[4];
#pragma unroll
  for (int c = 0; c < 4; ++c)
    qf[c] = *(const short8v*)&qbp[(size_t)(1 + q) * HD + c * 16 + h * 8];

  {
    const int hq = q >> 5;
    f32x16 sbh = {}, sb1 = {}, sb2 = {};
    const float* rh0 = rph + (size_t)(hq + 31 - qi) * HD + h * 8;
    const float* rw1 = rpw + (size_t)qi * HD + h * 8;
    const float* rw2 = rpw + (size_t)(qi < 31 ? 32 + qi : 62) * HD + h * 8;
#pragma unroll
    for (int c = 0; c < 4; ++c) {
      short8v a1 = pack8(*(const float4*)(rh0 + c * 16), *(const float4*)(rh0 + c * 16 + 4));
      sbh = __builtin_amdgcn_mfma_f32_32x32x16_bf16(a1, qf[c], sbh, 0, 0, 0);
      short8v a2 = pack8(*(const float4*)(rw1 + c * 16), *(const float4*)(rw1 + c * 16 + 4));
      sb1 = __builtin_amdgcn_mfma_f32_32x32x16_bf16(a2, qf[c], sb1, 0, 0, 0);
      short8v a3 = pack8(*(const float4*)(rw2 + c * 16), *(const float4*)(rw2 + c * 16 + 4));
      sb2 = __builtin_amdgcn_mfma_f32_32x32x16_bf16(a3, qf[c], sb2, 0, 0, 0);
    }
#pragma unroll
    for (int r = 0; r < 16; ++r) {
      const int kh = (r & 3) + 8 * (r >> 2) + 4 * h;
      bh_lds[row][kh]   = sbh[r] * L2E;
      T16[row][kh]      = f2b(sb1[r] * L2E);
      T16[row][kh + 32] = f2b(sb2[r] * L2E);
    }
    if (h == 0) { bh_lds[row][32] = 0.f; bh_lds[row][33] = 0.f; }
  }
  __syncthreads();

  float bwv[16];
#pragma unroll
  for (int r = 0; r < 16; ++r) {
    const int kvS = (r & 3) + 8 * (r >> 2) + 4 * h;
    const int kw = (kvS + 31) & 31;
    bwv[r] = b2f(T16[row][qi - kw + 31]);
  }
  __syncthreads();
  for (int i = t; i < 1088; i += 256)
    ctm[i] = (i <= 1024) ? MCOL : -2e30f;
  __syncthreads();

  const float mi_s = mask_f[b * N_ + 1 + q];
  const bool mzero = (mi_s == 0.f);
  const float* ctp = mzero ? ctm : ct_lds;
  const float h0sel = (h == 0) ? 1.f : 0.f;
  float m_lm = -1e30f, l_lane = 0.f;
  float bh_prev = -bwv[0];
  f32x16 oaccA = {}, oaccB = {};

  const char* kptr = (const char*)kbp + lane * 16;
  const char* vptr = (const char*)vbp + lane * 16;

  short8v kf[4];
#pragma unroll
  for (int c = 0; c < 4; ++c) kf[c] = *(const short8v*)(kptr + c * 1024);
  kptr += 4096;
  f32x16 sP = {}, sQ = {};
  sP = __builtin_amdgcn_mfma_f32_32x32x16_bf16(kf[0], qf[0], sP, 0, 0, 0);
  sP = __builtin_amdgcn_mfma_f32_32x32x16_bf16(kf[1], qf[1], sP, 0, 0, 0);
  sP = __builtin_amdgcn_mfma_f32_32x32x16_bf16(kf[2], qf[2], sP, 0, 0, 0);
  sP = __builtin_amdgcn_mfma_f32_32x32x16_bf16(kf[3], qf[3], sP, 0, 0, 0);

#define AITER(KT, SC, SN, DOPREF)                                            \
  do {                                                                       \
    short8v vf00 = *(const short8v*)(vptr);                                  \
    short8v vf01 = *(const short8v*)(vptr + 1024);                           \
    short8v vf10 = *(const short8v*)(vptr + 2048);                           \
    short8v vf11 = *(const short8v*)(vptr + 3072);                           \
    vptr += 4096;                                                            \
    if (DOPREF) {                                                            \
      kf[0] = *(const short8v*)(kptr);                                       \
      kf[1] = *(const short8v*)(kptr + 1024);                                \
      kf[2] = *(const short8v*)(kptr + 2048);                                \
      kf[3] = *(const short8v*)(kptr + 3072);                                \
      kptr += 4096;                                                          \
    }                                                                        \
    const float bh_k = bh_lds[row][KT];                                      \
    const float bh_use = mzero ? 0.f : bh_k;                                 \
    f32x4 ct4[4];                                                            \
    ct4[0] = *(const f32x4*)&ctp[(KT) * 32 + h * 4];                         \
    ct4[1] = *(const f32x4*)&ctp[(KT) * 32 + 8 + h * 4];                     \
    ct4[2] = *(const f32x4*)&ctp[(KT) * 32 + 16 + h * 4];                    \
    ct4[3] = *(const f32x4*)&ctp[(KT) * 32 + 24 + h * 4];                    \
    float lgp[16];                                                           \
    _Pragma("unroll")                                                        \
    for (int r = 0; r < 16; ++r)                                             \
      lgp[r] = fmaf(SCL, SC[r], bwv[r] + ct4[r >> 2][r & 3]);                \
    lgp[0] = fmaf(h0sel, bh_prev - bh_use, lgp[0]);                          \
    bh_prev = bh_k;                                                          \
    float a0 = fmaxf(lgp[0], lgp[1]),  a1 = fmaxf(lgp[2], lgp[3]);           \
    float a2 = fmaxf(lgp[4], lgp[5]),  a3 = fmaxf(lgp[6], lgp[7]);           \
    float a4 = fmaxf(lgp[8], lgp[9]),  a5 = fmaxf(lgp[10], lgp[11]);         \
    float a6 = fmaxf(lgp[12], lgp[13]), a7 = fmaxf(lgp[14], lgp[15]);        \
    float tm = fmaxf(fmaxf(fmaxf(a0, a1), fmaxf(a2, a3)),                    \
                     fmaxf(fmaxf(a4, a5), fmaxf(a6, a7)));                   \
    tm = fmaxf(tm, __shfl_xor(tm, 32));                                      \
    const float tmT = tm + bh_use;                                           \
    if (__any(tmT > m_lm + THR_L)) {                                         \
      const float nm = fmaxf(m_lm, tmT);                                     \
      const float rf = fexp2(m_lm - nm);                                     \
      m_lm = nm; l_lane *= rf;                                               \
      _Pragma("unroll")                                                      \
      for (int r = 0; r < 16; ++r) { oaccA[r] *= rf; oaccB[r] *= rf; }       \
    }                                                                        \
    const float mm = bh_use - m_lm;                                          \
    float p[16];                                                             \
    _Pragma("unroll")                                                        \
    for (int r = 0; r < 16; ++r) p[r] = fexp2(lgp[r] + mm);                  \
    l_lane += (((p[0]+p[1])+(p[2]+p[3]))+((p[4]+p[5])+(p[6]+p[7])))          \
            + (((p[8]+p[9])+(p[10]+p[11]))+((p[12]+p[13])+(p[14]+p[15])));   \
    unsigned int x0 = cvtpk(p[0], p[1]),  x1 = cvtpk(p[2], p[3]);            \
    unsigned int z0 = cvtpk(p[4], p[5]),  z1 = cvtpk(p[6], p[7]);            \
    plswap(x0, z0); plswap(x1, z1);                                          \
    unsigned int y0 = cvtpk(p[8], p[9]),  y1 = cvtpk(p[10], p[11]);          \
    unsigned int w0_ = cvtpk(p[12], p[13]), w1_ = cvtpk(p[14], p[15]);       \
    plswap(y0, w0_); plswap(y1, w1_);                                        \
    union { unsigned int u[4]; short8v v; } uf1, uf2;                        \
    uf1.u[0] = x0; uf1.u[1] = x1; uf1.u[2] = z0; uf1.u[3] = z1;              \
    uf2.u[0] = y0; uf2.u[1] = y1; uf2.u[2] = w0_; uf2.u[3] = w1_;            \
    if (DOPREF) {                                                            \
      f32x16 sn = {};                                                        \
      sn = __builtin_amdgcn_mfma_f32_32x32x16_bf16(kf[0], qf[0], sn, 0, 0, 0); \
      sn = __builtin_amdgcn_mfma_f32_32x32x16_bf16(kf[1], qf[1], sn, 0, 0, 0); \
      sn = __builtin_amdgcn_mfma_f32_32x32x16_bf16(kf[2], qf[2], sn, 0, 0, 0); \
      sn = __builtin_amdgcn_mfma_f32_32x32x16_bf16(kf[3], qf[3], sn, 0, 0, 0); \
      SN = sn;                                                               \
    }                                                                        \
    oaccA = __builtin_amdgcn_mfma_f32_32x32x16_bf16(vf00, uf1.v, oaccA, 0, 0, 0); \
    oaccA = __builtin_amdgcn_mfma_f32_32x32x16_bf16(vf01, uf2.v, oaccA, 0, 0, 0); \
    oaccB = __builtin_amdgcn_mfma_f32_32x32x16_bf16(vf10, uf1.v, oaccB, 0, 0, 0); \
    oaccB = __builtin_amdgcn_mfma_f32_32x32x16_bf16(vf11, uf2.v, oaccB, 0, 0, 0); \
  } while (0)

  for (int kt2 = 0; kt2 < 16; ++kt2) {
    AITER(2 * kt2,     sP, sQ, true);
    AITER(2 * kt2 + 1, sQ, sP, true);
  }
  AITER(32, sP, sQ, false);
#undef AITER

  // RACE FIX barrier: ctm (aliased in T16) reads must finish before the
  // epilogue overwrites T16.
  __syncthreads();

  const float l_tot = l_lane + __shfl_xor(l_lane, 32);
  const float inv = 1.f / l_tot;
  char* tbase = (char*)&T16[0][0] + row * 128;
  const int rsw = (row & 7) << 4;
#pragma unroll
  for (int r = 0; r < 16; r += 2) {
    const int d = (r & 3) + 8 * (r >> 2) + 4 * h;
    const unsigned int uA = cvtpk(oaccA[r] * inv, oaccA[r + 1] * inv);
    const unsigned int uB = cvtpk(oaccB[r] * inv, oaccB[r + 1] * inv);
    const int bo1 = 2 * d, bo2 = 2 * d + 64;
    *(unsigned int*)(tbase + (((bo1 & ~15) ^ rsw) | (bo1 & 15))) = uA;
    *(unsigned int*)(tbase + (((bo2 & ~15) ^ rsw) | (bo2 & 15))) = uB;
  }
  const int q2 = lane >> 1, hb = lane & 1;
  const int srow = w * 32 + q2;
  const char* sbase = (const char*)&T16[0][0] + srow * 128;
  const int ssw = srow & 7;
  unsigned short* dst =
      ao + (size_t)(b * NSP + qw0 + q2) * DIM + head * HD + hb * 32;
#pragma unroll
  for (int i = 0; i < 4; ++i) {
    const int ci = hb * 4 + i;
    short8v v = *(const short8v*)(sbase + ((ci ^ ssw) << 4));
    *(short8v*)(dst + i * 8) = v;
  }
}

// ---------------- final pooling reduce ----------------
__global__ __launch_bounds__(256) void pool_stage2(
    const float* __restrict__ psum, const float* __restrict__ pmax,
    const float* __restrict__ pcnt, float* __restrict__ out)
{
  const int b = blockIdx.y;
  const int c = blockIdx.x * 256 + threadIdx.x;
  float s = 0.f, mx = -3.402823466e+38f;
#pragma unroll
  for (int z = 0; z < 8; ++z) {
    s  += psum[(size_t)(b * 8 + z) * 768 + c];
    mx  = fmaxf(mx, pmax[(size_t)(b * 8 + z) * 768 + c]);
  }
  const float cnt = pcnt[b];
  out[b * 1536 + c]       = s / (cnt + 1e-7f);
  out[b * 1536 + 768 + c] = mx;
}

// ---------------- launch ----------------
extern "C" void kernel_launch(void* const* d_in, const int* in_sizes, int n_in,
                              void* d_out, int out_size, void* d_ws, size_t ws_size,
                              hipStream_t stream) {
  const float* x      = (const float*)d_in[0];
  const unsigned char* mraw = (const unsigned char*)d_in[1];
  const float* qkv_w  = (const float*)d_in[2];
  const float* qkv_b  = (const float*)d_in[3];
  const float* proj_w = (const float*)d_in[4];
  const float* proj_b = (const float*)d_in[5];
  const float* rph    = (const float*)d_in[6];
  const float* rpw    = (const float*)d_in[7];

  char* ws = (char*)d_ws;
  float*          mask_f = (float*)(ws + OFF_MASK);
  float*          pcnt   = (float*)(ws + OFF_PC);
  unsigned short* qkvwT  = (unsigned short*)(ws + OFF_QKVWT);
  unsigned short* projwT = (unsigned short*)(ws + OFF_PROJWT);
  unsigned short* qW     = (unsigned short*)(ws + OFF_Q);
  unsigned short* kW     = (unsigned short*)(ws + OFF_K);
  unsigned short* vW     = (unsigned short*)(ws + OFF_V);
  unsigned short* aoW    = (unsigned short*)(ws + OFF_AO);
  float*          psum   = (float*)(ws + OFF_PS);
  float*          pmax   = (float*)(ws + OFF_PM);
  unsigned short* xb     = (unsigned short*)(ws + OFF_XB);

  preproc<<<4449, 256, 0, stream>>>(mraw, mask_f, pcnt, kW, vW,
                                    qkv_w, proj_w, qkvwT, projwT, x, xb);

  gemm_bf16<0, 18, 1170><<<1170, 256, 0, stream>>>(
      xb, qkvwT, qkv_b, qW, kW, vW, nullptr, nullptr, nullptr, 8200);

  attn_mfma<<<768, 256, 0, stream>>>(qW, kW, vW, mask_f, rph, rpw, aoW);

  gemm_bf16<1, 6, 384><<<384, 256, 0, stream>>>(
      aoW, projwT, proj_b, nullptr, nullptr, nullptr,
      mask_f, psum, pmax, 8192);

  pool_stage2<<<dim3(3, B_), 256, 0, stream>>>(psum, pmax, pcnt, (float*)d_out);
}